// Round 4
// baseline (157.395 us; speedup 1.0000x reference)
//
#include <hip/hip_runtime.h>
#include <math.h>

#define F 128
#define HID 32
#define NH 4

__device__ __forceinline__ float silu_f(float x) {
    return x / (1.0f + __expf(-x));
}

// Scatter segment boundaries: starts[b] = first atom index with seg_id >= b.
__global__ void seg_starts_kernel(const int* __restrict__ seg, int* __restrict__ starts,
                                  int N, int B) {
    int i = blockIdx.x * blockDim.x + threadIdx.x;
    if (i >= N) return;
    int id = seg[i];
    if (i == 0) {
        for (int b = 0; b <= id; ++b) starts[b] = 0;
    } else {
        int prev = seg[i - 1];
        for (int b = prev + 1; b <= id; ++b) starts[b] = i;
    }
    if (i == N - 1) {
        for (int b = id + 1; b <= B; ++b) starts[b] = N;
    }
}

// K1: thread-per-atom key MLP, hand-software-pipelined row loads.
// Double-buffered 8x float4 chunks: next chunk's loads issued before current
// chunk's 1024 FMAs -> HBM latency hidden. W1 accessed uniformly (s_load).
__global__ __launch_bounds__(256, 4) void logits_kernel(
    const float* __restrict__ atom_fea, const float* __restrict__ W1,
    const float* __restrict__ b1, const float* __restrict__ W2,
    const float* __restrict__ b2, float* __restrict__ logits, int N) {
    int a = blockIdx.x * 256 + threadIdx.x;
    if (a >= N) return;
    const float4* row = (const float4*)(atom_fea + (size_t)a * F);

    float4 buf0[8], buf1[8];  // 64 VGPRs: explicit double buffer
    #pragma unroll
    for (int q = 0; q < 8; ++q) buf0[q] = row[q];

    float acc[HID];
    #pragma unroll
    for (int h = 0; h < HID; ++h) acc[h] = b1[h];

    #pragma unroll
    for (int c = 0; c < 4; ++c) {  // fully unrolled: buffer indices static
        const float* fr = (c & 1) ? (const float*)buf1 : (const float*)buf0;
        float4* nxt = (c & 1) ? buf0 : buf1;
        if (c < 3) {  // issue next chunk's 8 loads before current chunk's FMAs
            #pragma unroll
            for (int q = 0; q < 8; ++q) nxt[q] = row[(c + 1) * 8 + q];
        }
        #pragma unroll
        for (int k = 0; k < 32; ++k) {
            const float fk = fr[k];
            const float* w1r = &W1[(c * 32 + k) * HID];  // uniform -> s_load
            #pragma unroll
            for (int h = 0; h < HID; ++h) acc[h] = fmaf(fk, w1r[h], acc[h]);
        }
    }

    float p[NH] = {b2[0], b2[1], b2[2], b2[3]};
    #pragma unroll
    for (int h = 0; h < HID; ++h) {
        const float sv = silu_f(acc[h]);
        #pragma unroll
        for (int j = 0; j < NH; ++j) p[j] = fmaf(sv, W2[h * NH + j], p[j]);
    }
    *(float4*)&logits[(size_t)a * NH] = make_float4(p[0], p[1], p[2], p[3]);
}

// K2: wave-per-crystal segment softmax stats -> unnormalized exp weights wgt[N][4]
// and per-(crystal,head) 1/denom.
__global__ __launch_bounds__(256) void segstat_kernel(
    const float* __restrict__ logits, const int* __restrict__ starts,
    float* __restrict__ wgt, float* __restrict__ seginv, int B) {
    int b = blockIdx.x * 4 + (threadIdx.x >> 6);
    if (b >= B) return;
    int lane = threadIdx.x & 63;
    int start = starts[b], end = starts[b + 1];
    int head = lane & 3, ao = lane >> 2;
    float m = -INFINITY;
    for (int a0 = start; a0 < end; a0 += 16) {
        int a = a0 + ao;
        if (a < end) m = fmaxf(m, logits[(size_t)a * NH + head]);
    }
    #pragma unroll
    for (int d = 4; d < 64; d <<= 1) m = fmaxf(m, __shfl_xor(m, d));
    float s = 0.0f;
    for (int a0 = start; a0 < end; a0 += 16) {
        int a = a0 + ao;
        if (a < end) {
            float e = __expf(logits[(size_t)a * NH + head] - m);
            wgt[(size_t)a * NH + head] = e;
            s += e;
        }
    }
    #pragma unroll
    for (int d = 4; d < 64; d <<= 1) s += __shfl_xor(s, d);
    if (lane < 4) seginv[b * NH + lane] = (s > 0.0f) ? 1.0f / s : 0.0f;
}

// K3: block-per-crystal weighted feature sum with 8-deep load batching
// (L3-hit latency hiding) + fused output projection (8-deep Wp batching).
__global__ __launch_bounds__(256, 4) void readout_kernel(
    const float* __restrict__ atom_fea, const float* __restrict__ wgt,
    const float* __restrict__ seginv, const int* __restrict__ starts,
    const float* __restrict__ Wp, const float* __restrict__ bp,
    float* __restrict__ out) {
    __shared__ float sRed[4][NH][F];  // 8 KB
    __shared__ float sWacc[NH * F];   // 2 KB
    __shared__ float sPart[256];      // 1 KB
    const int t = threadIdx.x, b = blockIdx.x;
    const int start = starts[b], end = starts[b + 1];
    const int wv = t >> 6;            // wave id: atom-interleave group
    const int f0 = (t & 63) * 2;      // feature pair

    float acc[NH][2] = {};
    int a = start + wv;
    // pipelined groups: 8 atoms per wave per group (stride 4)
    for (; a + 28 < end; a += 32) {
        float4 w[8];
        float2 v[8];
        #pragma unroll
        for (int u = 0; u < 8; ++u) {
            const int aa = a + u * 4;
            w[u] = *(const float4*)&wgt[(size_t)aa * NH];
            v[u] = *(const float2*)&atom_fea[(size_t)aa * F + f0];
        }
        #pragma unroll
        for (int u = 0; u < 8; ++u) {
            acc[0][0] = fmaf(w[u].x, v[u].x, acc[0][0]); acc[0][1] = fmaf(w[u].x, v[u].y, acc[0][1]);
            acc[1][0] = fmaf(w[u].y, v[u].x, acc[1][0]); acc[1][1] = fmaf(w[u].y, v[u].y, acc[1][1]);
            acc[2][0] = fmaf(w[u].z, v[u].x, acc[2][0]); acc[2][1] = fmaf(w[u].z, v[u].y, acc[2][1]);
            acc[3][0] = fmaf(w[u].w, v[u].x, acc[3][0]); acc[3][1] = fmaf(w[u].w, v[u].y, acc[3][1]);
        }
    }
    for (; a < end; a += 4) {  // remainder
        const float4 w4 = *(const float4*)&wgt[(size_t)a * NH];
        const float2 v = *(const float2*)&atom_fea[(size_t)a * F + f0];
        acc[0][0] = fmaf(w4.x, v.x, acc[0][0]); acc[0][1] = fmaf(w4.x, v.y, acc[0][1]);
        acc[1][0] = fmaf(w4.y, v.x, acc[1][0]); acc[1][1] = fmaf(w4.y, v.y, acc[1][1]);
        acc[2][0] = fmaf(w4.z, v.x, acc[2][0]); acc[2][1] = fmaf(w4.z, v.y, acc[2][1]);
        acc[3][0] = fmaf(w4.w, v.x, acc[3][0]); acc[3][1] = fmaf(w4.w, v.y, acc[3][1]);
    }
    #pragma unroll
    for (int h = 0; h < NH; ++h) {
        sRed[wv][h][f0] = acc[h][0];
        sRed[wv][h][f0 + 1] = acc[h][1];
    }
    __syncthreads();
    {
        const int h = t >> 6;  // 256 threads cover 4 heads x 64 fpairs
        const float inv = seginv[b * NH + h];
        float s0 = sRed[0][h][f0] + sRed[1][h][f0] + sRed[2][h][f0] + sRed[3][h][f0];
        float s1 = sRed[0][h][f0 + 1] + sRed[1][h][f0 + 1] + sRed[2][h][f0 + 1] + sRed[3][h][f0 + 1];
        sWacc[h * F + f0] = s0 * inv;
        sWacc[h * F + f0 + 1] = s1 * inv;
    }
    __syncthreads();
    {
        const int f = t & 127, half = t >> 7;
        float sum = 0.0f;
        const float* wp = Wp + (size_t)(half * 256) * F + f;
        const float* wa = &sWacc[half * 256];
        for (int k0 = 0; k0 < 256; k0 += 8) {
            float wpv[8];
            #pragma unroll
            for (int u = 0; u < 8; ++u) wpv[u] = wp[(size_t)(k0 + u) * F];
            #pragma unroll
            for (int u = 0; u < 8; ++u) sum = fmaf(wa[k0 + u], wpv[u], sum);
        }
        sPart[t] = sum;
    }
    __syncthreads();
    if (t < 128) out[(size_t)b * F + t] = silu_f(sPart[t] + sPart[t + 128] + bp[t]);
}

extern "C" void kernel_launch(void* const* d_in, const int* in_sizes, int n_in,
                              void* d_out, int out_size, void* d_ws, size_t ws_size,
                              hipStream_t stream) {
    const float* atom_fea = (const float*)d_in[0];
    const int* seg = (const int*)d_in[1];
    const float* W1 = (const float*)d_in[3];
    const float* b1 = (const float*)d_in[4];
    const float* W2 = (const float*)d_in[5];
    const float* b2 = (const float*)d_in[6];
    const float* Wp = (const float*)d_in[7];
    const float* bp = (const float*)d_in[8];
    float* out = (float*)d_out;

    const int N = in_sizes[0] / F;
    const int B = out_size / F;

    // d_ws layout: starts | logits[N*4] | wgt[N*4] | seginv[B*4]
    char* ws = (char*)d_ws;
    int* starts = (int*)ws;
    size_t off = (((size_t)(B + 1) * sizeof(int)) + 255) & ~(size_t)255;
    float* logits = (float*)(ws + off);
    off += (size_t)N * NH * sizeof(float);
    float* wgt = (float*)(ws + off);
    off += (size_t)N * NH * sizeof(float);
    float* seginv = (float*)(ws + off);

    seg_starts_kernel<<<(N + 255) / 256, 256, 0, stream>>>(seg, starts, N, B);
    logits_kernel<<<(N + 255) / 256, 256, 0, stream>>>(atom_fea, W1, b1, W2, b2, logits, N);
    segstat_kernel<<<(B + 3) / 4, 256, 0, stream>>>(logits, starts, wgt, seginv, B);
    readout_kernel<<<B, 256, 0, stream>>>(atom_fea, wgt, seginv, starts, Wp, bp, out);
}

// Round 5
// 105.429 us; speedup vs baseline: 1.4929x; 1.4929x over previous
//
#include <hip/hip_runtime.h>
#include <math.h>

#define F 128
#define HID 32
#define NH 4
#define TILE 64
#define FSTR 130  // LDS row stride (floats): 2-way bank aliasing only (free)

__device__ __forceinline__ float silu_f(float x) {
    return x / (1.0f + __expf(-x));
}

// Scatter segment boundaries: starts[b] = first atom index with seg_id >= b.
__global__ void seg_starts_kernel(const int* __restrict__ seg, int* __restrict__ starts,
                                  int N, int B) {
    int i = blockIdx.x * blockDim.x + threadIdx.x;
    if (i >= N) return;
    int id = seg[i];
    if (i == 0) {
        for (int b = 0; b <= id; ++b) starts[b] = 0;
    } else {
        int prev = seg[i - 1];
        for (int b = prev + 1; b <= id; ++b) starts[b] = i;
    }
    if (i == N - 1) {
        for (int b = id + 1; b <= B; ++b) starts[b] = N;
    }
}

// One block (4 waves) per crystal.
// Per 64-atom tile: coalesced stage -> LDS; wave w = hid-group w of the MLP
// (lane = atom, W1 via wave-uniform s_load); cross-wave W2 reduce; online
// softmax (wave = head); weighted accumulate straight from the LDS tile.
__global__ __launch_bounds__(256) void fused2_kernel(
    const float* __restrict__ atom_fea, const int* __restrict__ starts,
    const float* __restrict__ W1, const float* __restrict__ b1,
    const float* __restrict__ W2, const float* __restrict__ b2,
    const float* __restrict__ Wp, const float* __restrict__ bp,
    float* __restrict__ out) {
    __shared__ float sFea[TILE * FSTR];     // 33.28 KB
    __shared__ float sP[NH * TILE * 5];     // 5.12 KB  partial logits [w][slot][5-pad]
    __shared__ float sTW[NH * TILE];        // 1 KB     exp-weights [head][slot]

    const int t = threadIdx.x;
    const int b = blockIdx.x;
    const int start = starts[b];
    const int end = starts[b + 1];
    const int wv = t >> 6;    // wave id: MLP hid-group AND softmax/accum head
    const int lane = t & 63;  // MLP atom slot AND accum f-pair
    const int w8 = __builtin_amdgcn_readfirstlane(wv * 8);  // force SGPR-uniform

    // hoist per-wave uniform weights
    float b1r[8], w2r[8][4];
    #pragma unroll
    for (int i = 0; i < 8; ++i) b1r[i] = b1[w8 + i];
    #pragma unroll
    for (int i = 0; i < 8; ++i)
        #pragma unroll
        for (int j = 0; j < 4; ++j) w2r[i][j] = W2[(w8 + i) * NH + j];
    const float b2w = b2[wv];

    float m_run = -INFINITY;
    float s_run = 0.0f;
    float acc0 = 0.0f, acc1 = 0.0f;

    for (int base = start; base < end; base += TILE) {
        const int T = min(TILE, end - base);

        // ---- stage: coalesced float4 global -> stride-130 LDS rows ----
        {
            const float4* src = (const float4*)(atom_fea + (size_t)base * F);
            for (int q = t; q < T * (F / 4); q += 256) {
                const float4 v = src[q];
                const int r = q >> 5, c = q & 31;
                float* dst = &sFea[r * FSTR + c * 4];
                *(float2*)dst = make_float2(v.x, v.y);
                *(float2*)(dst + 2) = make_float2(v.z, v.w);
            }
        }
        __syncthreads();

        // ---- MLP: wave wv computes hid[8wv..8wv+8) for atom=lane ----
        {
            float acc[8];
            #pragma unroll
            for (int i = 0; i < 8; ++i) acc[i] = b1r[i];
            const float* srow = &sFea[lane * FSTR];
            #pragma unroll 4
            for (int k = 0; k < F; k += 2) {
                const float2 f2 = *(const float2*)&srow[k];  // 8B aligned, 2-way free
                const float* wa = &W1[k * HID + w8];         // wave-uniform -> s_load
                const float* wb = &W1[(k + 1) * HID + w8];
                #pragma unroll
                for (int i = 0; i < 8; ++i) acc[i] = fmaf(f2.x, wa[i], acc[i]);
                #pragma unroll
                for (int i = 0; i < 8; ++i) acc[i] = fmaf(f2.y, wb[i], acc[i]);
            }
            float p[NH] = {0.0f, 0.0f, 0.0f, 0.0f};
            #pragma unroll
            for (int i = 0; i < 8; ++i) {
                const float sv = silu_f(acc[i]);
                #pragma unroll
                for (int j = 0; j < NH; ++j) p[j] = fmaf(sv, w2r[i][j], p[j]);
            }
            float* pd = &sP[(wv * TILE + lane) * 5];
            #pragma unroll
            for (int j = 0; j < NH; ++j) pd[j] = p[j];
        }
        __syncthreads();

        // ---- online softmax: wave wv owns head wv, lane = atom slot ----
        {
            float v;
            if (lane < T) {
                v = sP[(0 * TILE + lane) * 5 + wv] + sP[(1 * TILE + lane) * 5 + wv] +
                    sP[(2 * TILE + lane) * 5 + wv] + sP[(3 * TILE + lane) * 5 + wv] + b2w;
            } else {
                v = -INFINITY;
            }
            float mt = v;
            #pragma unroll
            for (int d = 1; d < 64; d <<= 1) mt = fmaxf(mt, __shfl_xor(mt, d));
            const float m_new = fmaxf(m_run, mt);
            const float r = __expf(m_run - m_new);  // first tile: exp(-inf)=0
            const float e = (lane < T) ? __expf(v - m_new) : 0.0f;
            sTW[wv * TILE + lane] = e;  // own-wave region; no barrier needed
            float se = e;
            #pragma unroll
            for (int d = 1; d < 64; d <<= 1) se += __shfl_xor(se, d);
            s_run = fmaf(s_run, r, se);
            m_run = m_new;
            acc0 *= r;
            acc1 *= r;
        }

        // ---- weighted accumulate from LDS tile: lane owns f-pair ----
        {
            const float* tw = &sTW[wv * TILE];
            const float* fbase = &sFea[lane * 2];
            #pragma unroll 4
            for (int a = 0; a < T; ++a) {
                const float w = tw[a];                              // LDS broadcast
                const float2 vv = *(const float2*)&fbase[a * FSTR]; // 2-way free
                acc0 = fmaf(w, vv.x, acc0);
                acc1 = fmaf(w, vv.y, acc1);
            }
        }
        __syncthreads();  // all waves done reading sFea/sP before next stage
    }

    const float inv = (s_run > 0.0f) ? 1.0f / s_run : 0.0f;

    // ---- epilogue: out[b] = silu(wacc @ Wp + bp); reuse sP as scratch ----
    float* sWacc = sP;        // 512 floats, k = h*F + f
    float* sPart = sP + 512;  // 256 floats
    sWacc[wv * F + lane * 2] = acc0 * inv;
    sWacc[wv * F + lane * 2 + 1] = acc1 * inv;
    __syncthreads();
    {
        const int f = t & 127, half = t >> 7;
        float sum = 0.0f;
        const float* wp = Wp + (size_t)(half * 256) * F + f;  // lane-contiguous
        const float* wa = &sWacc[half * 256];
        #pragma unroll 8
        for (int k = 0; k < 256; ++k) sum = fmaf(wa[k], wp[(size_t)k * F], sum);
        sPart[t] = sum;
    }
    __syncthreads();
    if (t < 128) out[(size_t)b * F + t] = silu_f(sPart[t] + sPart[t + 128] + bp[t]);
}

extern "C" void kernel_launch(void* const* d_in, const int* in_sizes, int n_in,
                              void* d_out, int out_size, void* d_ws, size_t ws_size,
                              hipStream_t stream) {
    const float* atom_fea = (const float*)d_in[0];
    const int* seg = (const int*)d_in[1];
    const float* W1 = (const float*)d_in[3];
    const float* b1 = (const float*)d_in[4];
    const float* W2 = (const float*)d_in[5];
    const float* b2 = (const float*)d_in[6];
    const float* Wp = (const float*)d_in[7];
    const float* bp = (const float*)d_in[8];
    float* out = (float*)d_out;

    const int N = in_sizes[0] / F;
    const int B = out_size / F;
    int* starts = (int*)d_ws;  // (B+1) ints

    seg_starts_kernel<<<(N + 255) / 256, 256, 0, stream>>>(seg, starts, N, B);
    fused2_kernel<<<B, 256, 0, stream>>>(atom_fea, starts, W1, b1, W2, b2, Wp, bp, out);
}

// Round 6
// 82.648 us; speedup vs baseline: 1.9044x; 1.2756x over previous
//
#include <hip/hip_runtime.h>
#include <hip/hip_bf16.h>
#include <math.h>

#define F 128
#define HID 32
#define NH 4
#define TILE 64

typedef __attribute__((ext_vector_type(8))) short bf16x8;
typedef __attribute__((ext_vector_type(4))) float f32x4;

__device__ __forceinline__ float silu_f(float x) {
    return x / (1.0f + __expf(-x));
}

__device__ __forceinline__ ushort f2bf(float f) {  // RNE float->bf16
    union { float f; uint u; } v; v.f = f;
    uint r = v.u + 0x7fffu + ((v.u >> 16) & 1u);
    return (ushort)(r >> 16);
}

// Scatter segment boundaries: starts[b] = first atom index with seg_id >= b.
__global__ void seg_starts_kernel(const int* __restrict__ seg, int* __restrict__ starts,
                                  int N, int B) {
    int i = blockIdx.x * blockDim.x + threadIdx.x;
    if (i >= N) return;
    int id = seg[i];
    if (i == 0) {
        for (int b = 0; b <= id; ++b) starts[b] = 0;
    } else {
        int prev = seg[i - 1];
        for (int b = prev + 1; b <= id; ++b) starts[b] = i;
    }
    if (i == N - 1) {
        for (int b = id + 1; b <= B; ++b) starts[b] = N;
    }
}

// One block (4 waves) per crystal. Per 64-atom tile:
//  stage: fp32 global -> bf16 LDS tile [64][128], 16B-chunk XOR swizzle (chunk ^= row&7)
//  MLP:   MFMA 16x16x32 bf16, D[h][a] = W1T(regs) @ feaT(tile row-reads); silu+W2 VALU
//  softmax: online, wave = head
//  phase C: weighted accumulate, lane owns (head, feat-oct), bf16 b128 reads
__global__ __launch_bounds__(256, 4) void fused3_kernel(
    const float* __restrict__ atom_fea, const int* __restrict__ starts,
    const float* __restrict__ W1, const float* __restrict__ b1,
    const float* __restrict__ W2, const float* __restrict__ b2,
    const float* __restrict__ Wp, const float* __restrict__ bp,
    float* __restrict__ out) {
    __shared__ ushort sFea[TILE * F];   // 16 KB bf16, swizzled
    __shared__ float sTL[TILE * 5];     // logits [atom][head], stride 5 (bank-spread)
    __shared__ float sTW[NH * 65];      // exp weights [head][atom], pad 65
    __shared__ float sR[NH];            // per-tile rescale per head
    __shared__ float sInv[NH];          // final 1/denom per head

    const int t = threadIdx.x;
    const int b = blockIdx.x;
    const int start = starts[b];
    const int end = starts[b + 1];
    const int wv = t >> 6;          // wave: MFMA atom-group AND softmax head AND phase-C atom-quarter
    const int lane = t & 63;
    const int lg = lane >> 4;       // 16-lane group
    const int l15 = lane & 15;
    const int ch = lane & 3;        // phase-C head
    const int co = (lane >> 2) & 15; // phase-C feat-oct (feats 8*co..8*co+7)

    // ---- one-time register preloads ----
    bf16x8 w1f[2][4];  // A-frags of W1T: [h-tile][k-step]; lane: h'=l15, k'=lg*8+j
    #pragma unroll
    for (int m0 = 0; m0 < 2; ++m0)
        #pragma unroll
        for (int kk = 0; kk < 4; ++kk) {
            bf16x8 fr;
            #pragma unroll
            for (int j = 0; j < 8; ++j)
                fr[j] = (short)f2bf(W1[(kk * 32 + lg * 8 + j) * HID + m0 * 16 + l15]);
            w1f[m0][kk] = fr;
        }
    float b1r[8], w2r[8][4];
    #pragma unroll
    for (int m0 = 0; m0 < 2; ++m0)
        #pragma unroll
        for (int r = 0; r < 4; ++r) {
            const int h = m0 * 16 + lg * 4 + r;
            b1r[m0 * 4 + r] = b1[h];
            #pragma unroll
            for (int j = 0; j < 4; ++j) w2r[m0 * 4 + r][j] = W2[h * NH + j];
        }
    const float b2r0 = b2[0], b2r1 = b2[1], b2r2 = b2[2], b2r3 = b2[3];  // uniform -> SGPR

    float m_run = -INFINITY, s_run = 0.0f;
    float acc8[8] = {0, 0, 0, 0, 0, 0, 0, 0};  // phase-C acc: feats 8*co+j of head ch (this wave's atom-quarter)

    for (int base = start; base < end; base += TILE) {
        const int T = min(TILE, end - base);

        // ---- stage: fp32 -> bf16 swizzled LDS ----
        {
            const float4* src = (const float4*)(atom_fea + (size_t)base * F);
            for (int q = t; q < T * (F / 4); q += 256) {
                const float4 v = src[q];
                const int r = q >> 5, c4 = q & 31;
                uint2 pk;
                pk.x = ((uint)f2bf(v.y) << 16) | f2bf(v.x);
                pk.y = ((uint)f2bf(v.w) << 16) | f2bf(v.z);
                const int chunk = (c4 >> 1) ^ (r & 7);
                *(uint2*)&sFea[r * F + chunk * 8 + (c4 & 1) * 4] = pk;
            }
            for (int q = T * (F / 4) + t; q < TILE * (F / 4); q += 256) {  // zero-fill tail rows
                const int r = q >> 5, c4 = q & 31;
                const int chunk = (c4 >> 1) ^ (r & 7);
                *(uint2*)&sFea[r * F + chunk * 8 + (c4 & 1) * 4] = make_uint2(0, 0);
            }
        }
        __syncthreads();

        // ---- MLP via MFMA: wave wv owns atoms 16wv..16wv+15 ----
        {
            f32x4 acc0, acc1;
            #pragma unroll
            for (int r = 0; r < 4; ++r) { acc0[r] = b1r[r]; acc1[r] = b1r[4 + r]; }
            const int row = wv * 16 + l15;
            #pragma unroll
            for (int kk = 0; kk < 4; ++kk) {
                const int chunk = (kk * 4 + lg) ^ (row & 7);
                const bf16x8 bf = *(const bf16x8*)&sFea[row * F + chunk * 8];
                acc0 = __builtin_amdgcn_mfma_f32_16x16x32_bf16(w1f[0][kk], bf, acc0, 0, 0, 0);
                acc1 = __builtin_amdgcn_mfma_f32_16x16x32_bf16(w1f[1][kk], bf, acc1, 0, 0, 0);
            }
            // silu + W2: per-lane 8 hids -> partial logits for its atom (col = l15)
            float p0 = 0, p1 = 0, p2 = 0, p3 = 0;
            #pragma unroll
            for (int r = 0; r < 4; ++r) {
                const float s0 = silu_f(acc0[r]);
                const float s1 = silu_f(acc1[r]);
                p0 = fmaf(s0, w2r[r][0], fmaf(s1, w2r[4 + r][0], p0));
                p1 = fmaf(s0, w2r[r][1], fmaf(s1, w2r[4 + r][1], p1));
                p2 = fmaf(s0, w2r[r][2], fmaf(s1, w2r[4 + r][2], p2));
                p3 = fmaf(s0, w2r[r][3], fmaf(s1, w2r[4 + r][3], p3));
            }
            p0 += __shfl_xor(p0, 16); p0 += __shfl_xor(p0, 32);
            p1 += __shfl_xor(p1, 16); p1 += __shfl_xor(p1, 32);
            p2 += __shfl_xor(p2, 16); p2 += __shfl_xor(p2, 32);
            p3 += __shfl_xor(p3, 16); p3 += __shfl_xor(p3, 32);
            if (lane < 16) {
                float* d = &sTL[(wv * 16 + lane) * 5];
                d[0] = p0 + b2r0; d[1] = p1 + b2r1; d[2] = p2 + b2r2; d[3] = p3 + b2r3;
            }
        }
        __syncthreads();

        // ---- online softmax: wave wv = head wv, lane = atom ----
        {
            const float v = (lane < T) ? sTL[lane * 5 + wv] : -INFINITY;
            float mt = v;
            #pragma unroll
            for (int d = 1; d < 64; d <<= 1) mt = fmaxf(mt, __shfl_xor(mt, d));
            const float m_new = fmaxf(m_run, mt);
            const float r = __expf(m_run - m_new);  // first tile: exp(-inf)=0
            const float e = (lane < T) ? __expf(v - m_new) : 0.0f;
            sTW[wv * 65 + lane] = e;
            float se = e;
            #pragma unroll
            for (int d = 1; d < 64; d <<= 1) se += __shfl_xor(se, d);
            s_run = fmaf(s_run, r, se);
            m_run = m_new;
            if (lane == 0) sR[wv] = r;
        }
        __syncthreads();

        // ---- phase C: wave wv covers atoms 16wv..16wv+15; lane = (head ch, oct co) ----
        {
            const float rr = sR[ch];
            #pragma unroll
            for (int i = 0; i < 8; ++i) acc8[i] *= rr;
            const int abase = wv * 16;
            #pragma unroll 4
            for (int i = 0; i < 16; ++i) {
                const int a = abase + i;
                const float w = sTW[ch * 65 + a];
                const int chunk = co ^ (a & 7);
                const uint4 d = *(const uint4*)&sFea[a * F + chunk * 8];
                acc8[0] = fmaf(w, __uint_as_float(d.x << 16), acc8[0]);
                acc8[1] = fmaf(w, __uint_as_float(d.x & 0xffff0000u), acc8[1]);
                acc8[2] = fmaf(w, __uint_as_float(d.y << 16), acc8[2]);
                acc8[3] = fmaf(w, __uint_as_float(d.y & 0xffff0000u), acc8[3]);
                acc8[4] = fmaf(w, __uint_as_float(d.z << 16), acc8[4]);
                acc8[5] = fmaf(w, __uint_as_float(d.z & 0xffff0000u), acc8[5]);
                acc8[6] = fmaf(w, __uint_as_float(d.w << 16), acc8[6]);
                acc8[7] = fmaf(w, __uint_as_float(d.w & 0xffff0000u), acc8[7]);
            }
        }
        __syncthreads();
    }

    if (lane == 0) sInv[wv] = (s_run > 0.0f) ? 1.0f / s_run : 0.0f;

    // ---- cross-wave reduce of phase-C partials (alias sFea) ----
    float* red = (float*)sFea;                    // 256 threads x 8 f32 = 8 KB
    float* sWacc = (float*)&sFea[4096];           // 512 f32 at +8 KB
    float* sPart = (float*)&sFea[4096 + 1024];    // 256 f32
    *(float4*)&red[t * 8] = make_float4(acc8[0], acc8[1], acc8[2], acc8[3]);
    *(float4*)&red[t * 8 + 4] = make_float4(acc8[4], acc8[5], acc8[6], acc8[7]);
    __syncthreads();
    if (t < 64) {
        const float inv = sInv[t & 3];
        const int h = t & 3, o = t >> 2;
        #pragma unroll
        for (int j = 0; j < 8; ++j) {
            const float s = red[t * 8 + j] + red[(64 + t) * 8 + j] +
                            red[(128 + t) * 8 + j] + red[(192 + t) * 8 + j];
            sWacc[h * F + o * 8 + j] = s * inv;
        }
    }
    __syncthreads();

    // ---- epilogue: out[b] = silu(wacc @ Wp + bp) ----
    {
        const int f = t & 127, half = t >> 7;
        float sum = 0.0f;
        const float* wp = Wp + (size_t)(half * 256) * F + f;
        const float* wa = &sWacc[half * 256];
        #pragma unroll 8
        for (int k = 0; k < 256; ++k) sum = fmaf(wa[k], wp[(size_t)k * F], sum);
        sPart[t] = sum;
    }
    __syncthreads();
    if (t < 128) out[(size_t)b * F + t] = silu_f(sPart[t] + sPart[t + 128] + bp[t]);
}

extern "C" void kernel_launch(void* const* d_in, const int* in_sizes, int n_in,
                              void* d_out, int out_size, void* d_ws, size_t ws_size,
                              hipStream_t stream) {
    const float* atom_fea = (const float*)d_in[0];
    const int* seg = (const int*)d_in[1];
    const float* W1 = (const float*)d_in[3];
    const float* b1 = (const float*)d_in[4];
    const float* W2 = (const float*)d_in[5];
    const float* b2 = (const float*)d_in[6];
    const float* Wp = (const float*)d_in[7];
    const float* bp = (const float*)d_in[8];
    float* out = (float*)d_out;

    const int N = in_sizes[0] / F;
    const int B = out_size / F;
    int* starts = (int*)d_ws;  // (B+1) ints

    seg_starts_kernel<<<(N + 255) / 256, 256, 0, stream>>>(seg, starts, N, B);
    fused3_kernel<<<B, 256, 0, stream>>>(atom_fea, starts, W1, b1, W2, b2, Wp, bp, out);
}